// Round 2
// baseline (235.809 us; speedup 1.0000x reference)
//
#include <hip/hip_runtime.h>
#include <hip/hip_bf16.h>
#include <stdint.h>

// ---------------------------------------------------------------------------
// SelfAttention: QKV = X@W + b ; S = QK^T/32 (mask -> -inf) ; O = softmax(S)@V
// B=4, S=2048, H=1024.  bf16 MFMA path.
// R10: 8-phase 256-tile schedule (T3+T4+T5) for all three GEMMs. R9 showed
//     the 2-phase counted-vmcnt structure caps at MfmaUtil ~23%: per-K-step
//     compute (160cy) can't cover HBM latency at 1-phase prefetch distance.
//     Now: 8 waves (512thr), BM=256, BK=64, double-buffered LDS; per phase
//     {ds_read subtile + stage 1 half-tile -> barrier -> MFMA quadrant ->
//     barrier}; vmcnt gates only at ph4/ph8 (N from stage assignment, never
//     0 in loop); s_setprio(1) around MFMA clusters. Prefetch distance is
//     4-7 phases (~600-1000cy) -> latency hidden by construction.
//     qkv: 256x256 (128KB LDS); scores/pv: 256x128 (96KB LDS).
// ---------------------------------------------------------------------------

typedef __attribute__((ext_vector_type(8))) short bf16x8;   // 8 bf16 = 4 VGPRs
typedef __attribute__((ext_vector_type(4))) float f32x4;

__device__ __forceinline__ void async_cp16(const void* g, void* l) {
  __builtin_amdgcn_global_load_lds(
      (const __attribute__((address_space(1))) void*)g,
      (__attribute__((address_space(3))) void*)l, 16, 0, 0);
}

#define FENCE() asm volatile("" ::: "memory")
#define BAR()                           \
  do {                                  \
    FENCE();                            \
    __builtin_amdgcn_s_barrier();       \
    FENCE();                            \
  } while (0)
#define VMW(N) asm volatile("s_waitcnt vmcnt(" #N ")" ::: "memory")

// --------------------------- fp32 -> bf16 convert ---------------------------
__global__ void cvt_f32_bf16(const float* __restrict__ s,
                             __hip_bfloat16* __restrict__ d, int n) {
  int i = (blockIdx.x * blockDim.x + threadIdx.x) * 4;
  if (i >= n) return;
  float4 f = *(const float4*)(s + i);
  __hip_bfloat16 o[4];
  o[0] = __float2bfloat16(f.x);
  o[1] = __float2bfloat16(f.y);
  o[2] = __float2bfloat16(f.z);
  o[3] = __float2bfloat16(f.w);
  *(ushort4*)(d + i) = *(const ushort4*)o;
}

// -------------------- fp32 -> bf16 transposed (W -> W^T) --------------------
__global__ void transpose_cvt_f32(const float* __restrict__ src, int srcld,
                                  __hip_bfloat16* __restrict__ dst, int dstld) {
  __shared__ float tile[32][33];
  int bx = blockIdx.x * 32;   // src col
  int by = blockIdx.y * 32;   // src row
  int tx = threadIdx.x, ty = threadIdx.y;
#pragma unroll
  for (int j = 0; j < 4; ++j)
    tile[ty + j * 8][tx] = src[(int64_t)(by + ty + j * 8) * srcld + bx + tx];
  __syncthreads();
#pragma unroll
  for (int j = 0; j < 4; ++j)
    dst[(int64_t)(bx + ty + j * 8) * dstld + by + tx] =
        __float2bfloat16(tile[tx][ty + j * 8]);
}

// ------------------------------ mask scan ----------------------------------
__global__ __launch_bounds__(256) void mask_scan(const int* __restrict__ mask,
                                                 int* __restrict__ idx,
                                                 int* __restrict__ cnt,
                                                 int* __restrict__ cnt_pad) {
  const int b = blockIdx.x;
  mask += b * 2048;
  idx += b * 2048;
  const int t = threadIdx.x;
  const int lane = t & 63, wave = t >> 6;

  int keep[8];
  int local = 0;
#pragma unroll
  for (int j = 0; j < 8; ++j) {
    keep[j] = (mask[t * 8 + j] == 0);
    local += keep[j];
  }
  int pre = local;  // inclusive wave scan
#pragma unroll
  for (int off = 1; off <= 32; off <<= 1) {
    int n = __shfl_up(pre, off, 64);
    if (lane >= off) pre += n;
  }
  __shared__ int wsum[4];
  if (lane == 63) wsum[wave] = pre;
  __syncthreads();
  int base = 0;
  for (int w = 0; w < wave; ++w) base += wsum[w];
  int excl = base + pre - local;
#pragma unroll
  for (int j = 0; j < 8; ++j)
    if (keep[j]) idx[excl++] = t * 8 + j;
  if (t == 255) {
    int tot = base + pre;
    cnt[b] = tot;
    int p = (tot + 255) & ~255;     // 256-tile aligned for 8-phase GEMMs
    cnt_pad[b] = p > 2048 ? 2048 : p;
  }
}

// --------------------------- merged Q+K+V GEMM -----------------------------
// grid (96, 1, B), 512 thr.  f<32: Q tiles (8m x 4n); f>=32: KV (8m x 8n).
// BM=BN=256, BK=64, 8 waves (2M x 4N), per-wave C = 128x64.
// LDS 128KB: A [2buf][256][64] @0, B [2buf][256][64] @32768 el.
__global__ __launch_bounds__(512, 2) void gemm_qkv(
    const __hip_bfloat16* __restrict__ Xb, const __hip_bfloat16* __restrict__ Wt,
    const float* __restrict__ bias, const int* __restrict__ idx,
    const int* __restrict__ cnt, const int* __restrict__ cnt_pad,
    __hip_bfloat16* __restrict__ Q, __hip_bfloat16* __restrict__ Kc,
    __hip_bfloat16* __restrict__ Vt) {
  const int z = blockIdx.z;
  const int f = blockIdx.x;
  int m0, n0;
  bool isQ;
  if (f < 32) {
    int xcd = f & 7, loc = f >> 3;
    isQ = true;
    m0 = (loc * 2 + (xcd >> 2)) * 256;
    n0 = (xcd & 3) * 256;
  } else {
    int g = f - 32, xcd = g & 7, loc = g >> 3;
    isQ = false;
    m0 = ((loc & 3) * 2 + (xcd >> 2)) * 256;
    n0 = ((loc >> 2) * 4 + (xcd & 3)) * 256;
  }
  if (!isQ && m0 >= cnt_pad[z]) return;
  const __hip_bfloat16* A = Xb + (int64_t)z * 2048 * 1024;
  const __hip_bfloat16* Bt = Wt + (isQ ? 0 : (int64_t)1024 * 1024);
  const float* bv = bias + (isQ ? 0 : 1024);

  const int tid = threadIdx.x;
  const int wave = tid >> 6, lane = tid & 63;
  const int quad = lane >> 4, tr = lane & 15, t7 = tr & 7;
  const int wm = wave >> 2, wn = wave & 3;

  __shared__ __hip_bfloat16 ls[65536];  // 128 KB

  const int srow = lane >> 3;
  const int kcs = ((lane & 7) ^ srow) * 8;   // pre-swizzled k-chunk (elements)

  // Per-wave staging: A half = 16 chunks (2/wave), B half = 16 chunks (2/wave)
  const __hip_bfloat16* pA[2][2];
  const __hip_bfloat16* pB[2][2];
  int aoff[2][2], boff[2][2];
  {
    const int cz = isQ ? 0 : cnt[z];
    const int* idxz = idx + z * 2048;
#pragma unroll
    for (int h = 0; h < 2; ++h)
#pragma unroll
      for (int j = 0; j < 2; ++j) {
        int chunk = wave * 2 + j;
        int rl = h * 128 + chunk * 8 + srow;
        int ar = m0 + rl;
        if (!isQ) ar = (ar < cz) ? idxz[ar] : 0;
        pA[h][j] = A + (int64_t)ar * 1024 + kcs;
        pB[h][j] = Bt + (int64_t)(n0 + rl) * 1024 + kcs;
        aoff[h][j] = (h * 128 + chunk * 8) * 64;
        boff[h][j] = 32768 + (h * 128 + chunk * 8) * 64;
      }
  }

  f32x4 acc[8][4];
#pragma unroll
  for (int mi = 0; mi < 8; ++mi)
#pragma unroll
    for (int ni = 0; ni < 4; ++ni) acc[mi][ni] = (f32x4){0.f, 0.f, 0.f, 0.f};

  bf16x8 af[4], bf[4];

#define STA(buf, h, t)                                              \
  do {                                                              \
    async_cp16(pA[h][0] + (t) * 64, ls + (buf)*16384 + aoff[h][0]); \
    async_cp16(pA[h][1] + (t) * 64, ls + (buf)*16384 + aoff[h][1]); \
  } while (0)
#define STB(buf, h, t)                                              \
  do {                                                              \
    async_cp16(pB[h][0] + (t) * 64, ls + (buf)*16384 + boff[h][0]); \
    async_cp16(pB[h][1] + (t) * 64, ls + (buf)*16384 + boff[h][1]); \
  } while (0)
#define DSA(buf, h, s)                                                        \
  do {                                                                        \
    const __hip_bfloat16* LA = ls + (buf)*16384;                              \
    _Pragma("unroll") for (int j = 0; j < 4; ++j) af[j] =                     \
        *(const bf16x8*)(LA + (wm * 128 + (h)*64 + j * 16 + tr) * 64 +        \
                         ((((s) << 2) | quad) ^ t7) * 8);                     \
  } while (0)
#define DSB(buf, s)                                                           \
  do {                                                                        \
    const __hip_bfloat16* LB = ls + 32768 + (buf)*16384;                      \
    _Pragma("unroll") for (int n = 0; n < 4; ++n) bf[n] =                     \
        *(const bf16x8*)(LB + (wn * 64 + n * 16 + tr) * 64 +                  \
                         ((((s) << 2) | quad) ^ t7) * 8);                     \
  } while (0)
#define MF(h)                                                                 \
  do {                                                                        \
    __builtin_amdgcn_s_setprio(1);                                            \
    _Pragma("unroll") for (int j = 0; j < 4; ++j)                             \
        _Pragma("unroll") for (int n = 0; n < 4; ++n) acc[(h)*4 + j][n] =     \
            __builtin_amdgcn_mfma_f32_16x16x32_bf16(af[j], bf[n],             \
                                                    acc[(h)*4 + j][n], 0, 0,  \
                                                    0);                       \
    __builtin_amdgcn_s_setprio(0);                                            \
  } while (0)

  // Prologue: buf0 = tile0 (4 halves), B-buf1-h0 = tile1.
  STA(0, 0, 0); STA(0, 1, 0); STB(0, 0, 0); STB(0, 1, 0);
  STB(1, 0, 1);
  VMW(2);
  BAR();

  for (int it = 0; it < 8; ++it) {   // NT=16 K-tiles, 2 per iteration
    const int t1 = 2 * it + 1;
    const int tn0 = (2 * it + 2 < 16) ? 2 * it + 2 : 15;
    const int tn1 = (2 * it + 3 < 16) ? 2 * it + 3 : 15;
    // ph1
    DSA(0, 0, 0); DSB(0, 0); STB(1, 1, t1); BAR(); MF(0); BAR();
    // ph2
    DSA(0, 1, 0);            STA(1, 0, t1); BAR(); MF(1); BAR();
    // ph3
    DSA(0, 0, 1); DSB(0, 1); STA(1, 1, t1); BAR(); MF(0); BAR();
    // ph4  (gate buf1: all but ph4's 2 loads complete)
    DSA(0, 1, 1);            STB(0, 0, tn0); VMW(2); BAR(); MF(1); BAR();
    // ph5
    DSA(1, 0, 0); DSB(1, 0); STB(0, 1, tn0); BAR(); MF(0); BAR();
    // ph6
    DSA(1, 1, 0);            STA(0, 0, tn0); BAR(); MF(1); BAR();
    // ph7
    DSA(1, 0, 1); DSB(1, 1); STA(0, 1, tn0); BAR(); MF(0); BAR();
    // ph8  (gate buf0 for next iter)
    DSA(1, 1, 1);            STB(1, 0, tn1); VMW(2); BAR(); MF(1); BAR();
  }
  asm volatile("s_waitcnt vmcnt(0)" ::: "memory");  // drain stray tail stages
#undef STA
#undef STB
#undef DSA
#undef DSB
#undef MF

  // Epilogue. D element (row,col) in 16x16 tile = (quad*4 + r, tr)  [m89]
  const int rowbase = m0 + wm * 128;
  const int colbase = n0 + wn * 64;
  if (isQ) {
    __hip_bfloat16* C = Q + (int64_t)z * 2048 * 1024;
#pragma unroll
    for (int ni = 0; ni < 4; ++ni) {
      int col = colbase + ni * 16 + tr;
      float bb = bv[col];
#pragma unroll
      for (int mi = 0; mi < 8; ++mi) {
        int row = rowbase + mi * 16 + quad * 4;
#pragma unroll
        for (int r = 0; r < 4; ++r)
          C[(int64_t)(row + r) * 1024 + col] =
              __float2bfloat16(acc[mi][ni][r] + bb);
      }
    }
  } else if (n0 < 1024) {  // K half
    __hip_bfloat16* C = Kc + (int64_t)z * 2048 * 1024;
#pragma unroll
    for (int ni = 0; ni < 4; ++ni) {
      int col = colbase + ni * 16 + tr;
      float bb = bv[col];
#pragma unroll
      for (int mi = 0; mi < 8; ++mi) {
        int row = rowbase + mi * 16 + quad * 4;
#pragma unroll
        for (int r = 0; r < 4; ++r)
          C[(int64_t)(row + r) * 1024 + col] =
              __float2bfloat16(acc[mi][ni][r] + bb);
      }
    }
  } else {  // V half -> LDS transpose (two 128-d passes) -> coalesced Vt rows
    __hip_bfloat16* Vz = Vt + (int64_t)z * 1024 * 2048;
    const int d0 = n0 - 1024;
#pragma unroll
    for (int p = 0; p < 2; ++p) {
      __syncthreads();
      if ((wn >> 1) == p) {  // waves covering d-cols [p*128, p*128+128)
#pragma unroll
        for (int ni = 0; ni < 4; ++ni) {
          int cl = (wn & 1) * 64 + ni * 16 + tr;      // pass-local d [0,128)
          float bb = bv[colbase + ni * 16 + tr];
#pragma unroll
          for (int mi = 0; mi < 8; ++mi) {
            int rl = wm * 128 + mi * 16 + quad * 4;   // block-local key
            __hip_bfloat16 h4[4];
#pragma unroll
            for (int r = 0; r < 4; ++r)
              h4[r] = __float2bfloat16(acc[mi][ni][r] + bb);
            *(ushort4*)(ls + cl * 264 + rl) = *(const ushort4*)h4;
          }
        }
      }
      __syncthreads();
      const int dloc = tid >> 2;   // [0,128)
      const int sg0 = tid & 3;
#pragma unroll
      for (int i = 0; i < 8; ++i) {
        int seg = i * 4 + sg0;     // [0,32) -> keys seg*8..seg*8+7
        bf16x8 v = *(const bf16x8*)(ls + dloc * 264 + seg * 8);
        *(bf16x8*)(Vz + (int64_t)(d0 + p * 128 + dloc) * 2048 + m0 + seg * 8) =
            v;
      }
    }
  }
}

// ------------------------ scores GEMM + fused exp --------------------------
// e = exp2(scale2 * (Q@Kc^T)) bf16; cols >= cnt -> 0. Row sums -> atomicAdd.
// BM=256, BN=128, BK=64, 8 waves (2M x 4N), per-wave C = 128x32.
// LDS 96KB: A [2][256][64] @0, B [2][128][64] @32768 el.
__global__ __launch_bounds__(512, 2) void gemm_scores(
    const __hip_bfloat16* __restrict__ Qb, const __hip_bfloat16* __restrict__ Kc,
    __hip_bfloat16* __restrict__ Sc, float* __restrict__ rowsum,
    const int* __restrict__ cnt, const int* __restrict__ cnt_pad,
    float scale2) {
  const int z = blockIdx.z;
  const int f = blockIdx.x;
  const int xcd = f & 7, loc = f >> 3;
  const int m0 = (loc & 7) * 256;
  const int n0 = ((loc >> 3) * 8 + xcd) * 128;
  if (n0 >= cnt_pad[z]) return;
  const __hip_bfloat16* A = Qb + (int64_t)z * 2048 * 1024;
  const __hip_bfloat16* Bt = Kc + (int64_t)z * 2048 * 1024;

  const int tid = threadIdx.x;
  const int wave = tid >> 6, lane = tid & 63;
  const int quad = lane >> 4, tr = lane & 15, t7 = tr & 15 & 7;
  const int wm = wave >> 2, wn = wave & 3;

  __shared__ __hip_bfloat16 ls[49152];  // 96 KB

  const int srow = lane >> 3;
  const int kcs = ((lane & 7) ^ srow) * 8;

  const __hip_bfloat16* pA[2][2];
  const __hip_bfloat16* pB[2];
  int aoff[2][2], boff[2];
  {
#pragma unroll
    for (int h = 0; h < 2; ++h) {
#pragma unroll
      for (int j = 0; j < 2; ++j) {
        int chunk = wave * 2 + j;
        int rl = h * 128 + chunk * 8 + srow;
        pA[h][j] = A + (int64_t)(m0 + rl) * 1024 + kcs;
        aoff[h][j] = (h * 128 + chunk * 8) * 64;
      }
      int rlb = h * 64 + wave * 8 + srow;
      pB[h] = Bt + (int64_t)(n0 + rlb) * 1024 + kcs;
      boff[h] = 32768 + (h * 64 + wave * 8) * 64;
    }
  }

  f32x4 acc[8][2];
#pragma unroll
  for (int mi = 0; mi < 8; ++mi)
#pragma unroll
    for (int ni = 0; ni < 2; ++ni) acc[mi][ni] = (f32x4){0.f, 0.f, 0.f, 0.f};

  bf16x8 af[4], bf[2];

#define STA(buf, h, t)                                              \
  do {                                                              \
    async_cp16(pA[h][0] + (t) * 64, ls + (buf)*16384 + aoff[h][0]); \
    async_cp16(pA[h][1] + (t) * 64, ls + (buf)*16384 + aoff[h][1]); \
  } while (0)
#define STB(buf, h, t) \
  async_cp16(pB[h] + (t) * 64, ls + (buf)*8192 + boff[h])
#define DSA(buf, h, s)                                                        \
  do {                                                                        \
    const __hip_bfloat16* LA = ls + (buf)*16384;                              \
    _Pragma("unroll") for (int j = 0; j < 4; ++j) af[j] =                     \
        *(const bf16x8*)(LA + (wm * 128 + (h)*64 + j * 16 + tr) * 64 +        \
                         ((((s) << 2) | quad) ^ t7) * 8);                     \
  } while (0)
#define DSB(buf, s)                                                           \
  do {                                                                        \
    const __hip_bfloat16* LB = ls + 32768 + (buf)*8192;                       \
    _Pragma("unroll") for (int n = 0; n < 2; ++n) bf[n] =                     \
        *(const bf16x8*)(LB + (wn * 32 + n * 16 + tr) * 64 +                  \
                         ((((s) << 2) | quad) ^ t7) * 8);                     \
  } while (0)
#define MF(h)                                                                 \
  do {                                                                        \
    __builtin_amdgcn_s_setprio(1);                                            \
    _Pragma("unroll") for (int j = 0; j < 4; ++j)                             \
        _Pragma("unroll") for (int n = 0; n < 2; ++n) acc[(h)*4 + j][n] =     \
            __builtin_amdgcn_mfma_f32_16x16x32_bf16(af[j], bf[n],             \
                                                    acc[(h)*4 + j][n], 0, 0,  \
                                                    0);                       \
    __builtin_amdgcn_s_setprio(0);                                            \
  } while (0)

  STA(0, 0, 0); STA(0, 1, 0); STB(0, 0, 0); STB(0, 1, 0);
  STB(1, 0, 1);
  VMW(1);
  BAR();

  for (int it = 0; it < 8; ++it) {
    const int t1 = 2 * it + 1;
    const int tn0 = (2 * it + 2 < 16) ? 2 * it + 2 : 15;
    const int tn1 = (2 * it + 3 < 16) ? 2 * it + 3 : 15;
    DSA(0, 0, 0); DSB(0, 0); STB(1, 1, t1); BAR(); MF(0); BAR();
    DSA(0, 1, 0);            STA(1, 0, t1); BAR(); MF(1); BAR();
    DSA(0, 0, 1); DSB(0, 1); STA(1, 1, t1); BAR(); MF(0); BAR();
    DSA(0, 1, 1);            STB(0, 0, tn0); VMW(1); BAR(); MF(1); BAR();
    DSA(1, 0, 0); DSB(1, 0); STB(0, 1, tn0); BAR(); MF(0); BAR();
    DSA(1, 1, 0);            STA(0, 0, tn0); BAR(); MF(1); BAR();
    DSA(1, 0, 1); DSB(1, 1); STA(0, 1, tn0); BAR(); MF(0); BAR();
    DSA(1, 1, 1);            STB(1, 0, tn1); VMW(1); BAR(); MF(1); BAR();
  }
  asm volatile("s_waitcnt vmcnt(0)" ::: "memory");
#undef STA
#undef STB
#undef DSA
#undef DSB
#undef MF

  const int rowbase = m0 + wm * 128;
  const int colbase = n0 + wn * 32;
  const int cn = cnt[z];
  __hip_bfloat16* C = Sc + (int64_t)z * 2048 * 2048;

  float psum[8][4];
#pragma unroll
  for (int mi = 0; mi < 8; ++mi)
#pragma unroll
    for (int r = 0; r < 4; ++r) psum[mi][r] = 0.f;

#pragma unroll
  for (int ni = 0; ni < 2; ++ni) {
    int col = colbase + ni * 16 + tr;
    bool valid = (col < cn);
#pragma unroll
    for (int mi = 0; mi < 8; ++mi) {
      int row = rowbase + mi * 16 + quad * 4;
#pragma unroll
      for (int r = 0; r < 4; ++r) {
        float e = valid ? exp2f(acc[mi][ni][r] * scale2) : 0.f;
        C[(int64_t)(row + r) * 2048 + col] = __float2bfloat16(e);
        psum[mi][r] += e;
      }
    }
  }
#pragma unroll
  for (int off = 1; off <= 8; off <<= 1)
#pragma unroll
    for (int mi = 0; mi < 8; ++mi)
#pragma unroll
      for (int r = 0; r < 4; ++r)
        psum[mi][r] += __shfl_xor(psum[mi][r], off, 64);
  if (tr == 0) {
    float* rs = rowsum + z * 2048 + rowbase;
#pragma unroll
    for (int mi = 0; mi < 8; ++mi)
#pragma unroll
      for (int r = 0; r < 4; ++r)
        atomicAdd(&rs[mi * 16 + quad * 4 + r], psum[mi][r]);
  }
}

// --------------------------- PV GEMM + normalize ---------------------------
// out = (E @ Vt^T) / rowsum[row]  (fp32). K = cnt_pad[z]. BM=256, BN=128.
__global__ __launch_bounds__(512, 2) void gemm_pv(
    const __hip_bfloat16* __restrict__ Sc, const __hip_bfloat16* __restrict__ Vt,
    float* __restrict__ out, const float* __restrict__ rowsum,
    const int* __restrict__ cnt_pad) {
  const int z = blockIdx.z;
  const int f = blockIdx.x;
  const int m0 = (f >> 3) * 256;
  const int n0 = (f & 7) * 128;
  const int Ks = cnt_pad[z];
  const __hip_bfloat16* A = Sc + (int64_t)z * 2048 * 2048;
  const __hip_bfloat16* Bt = Vt + (int64_t)z * 1024 * 2048;

  const int tid = threadIdx.x;
  const int wave = tid >> 6, lane = tid & 63;
  const int quad = lane >> 4, tr = lane & 15, t7 = tr & 7;
  const int wm = wave >> 2, wn = wave & 3;

  __shared__ __hip_bfloat16 ls[49152];

  const int srow = lane >> 3;
  const int kcs = ((lane & 7) ^ srow) * 8;

  const __hip_bfloat16* pA[2][2];
  const __hip_bfloat16* pB[2];
  int aoff[2][2], boff[2];
  {
#pragma unroll
    for (int h = 0; h < 2; ++h) {
#pragma unroll
      for (int j = 0; j < 2; ++j) {
        int chunk = wave * 2 + j;
        int rl = h * 128 + chunk * 8 + srow;
        pA[h][j] = A + (int64_t)(m0 + rl) * 2048 + kcs;
        aoff[h][j] = (h * 128 + chunk * 8) * 64;
      }
      int rlb = h * 64 + wave * 8 + srow;
      pB[h] = Bt + (int64_t)(n0 + rlb) * 2048 + kcs;
      boff[h] = 32768 + (h * 64 + wave * 8) * 64;
    }
  }

  f32x4 acc[8][2];
#pragma unroll
  for (int mi = 0; mi < 8; ++mi)
#pragma unroll
    for (int ni = 0; ni < 2; ++ni) acc[mi][ni] = (f32x4){0.f, 0.f, 0.f, 0.f};

  bf16x8 af[4], bf[2];

#define STA(buf, h, t)                                              \
  do {                                                              \
    async_cp16(pA[h][0] + (t) * 64, ls + (buf)*16384 + aoff[h][0]); \
    async_cp16(pA[h][1] + (t) * 64, ls + (buf)*16384 + aoff[h][1]); \
  } while (0)
#define STB(buf, h, t) \
  async_cp16(pB[h] + (t) * 64, ls + (buf)*8192 + boff[h])
#define DSA(buf, h, s)                                                        \
  do {                                                                        \
    const __hip_bfloat16* LA = ls + (buf)*16384;                              \
    _Pragma("unroll") for (int j = 0; j < 4; ++j) af[j] =                     \
        *(const bf16x8*)(LA + (wm * 128 + (h)*64 + j * 16 + tr) * 64 +        \
                         ((((s) << 2) | quad) ^ t7) * 8);                     \
  } while (0)
#define DSB(buf, s)                                                           \
  do {                                                                        \
    const __hip_bfloat16* LB = ls + 32768 + (buf)*8192;                       \
    _Pragma("unroll") for (int n = 0; n < 2; ++n) bf[n] =                     \
        *(const bf16x8*)(LB + (wn * 32 + n * 16 + tr) * 64 +                  \
                         ((((s) << 2) | quad) ^ t7) * 8);                     \
  } while (0)
#define MF(h)                                                                 \
  do {                                                                        \
    __builtin_amdgcn_s_setprio(1);                                            \
    _Pragma("unroll") for (int j = 0; j < 4; ++j)                             \
        _Pragma("unroll") for (int n = 0; n < 2; ++n) acc[(h)*4 + j][n] =     \
            __builtin_amdgcn_mfma_f32_16x16x32_bf16(af[j], bf[n],             \
                                                    acc[(h)*4 + j][n], 0, 0,  \
                                                    0);                       \
    __builtin_amdgcn_s_setprio(0);                                            \
  } while (0)

  const int NT = Ks >> 6;       // K-tiles (multiple of 4)
  const int NITER = NT >> 1;
  const int NTm1 = NT - 1;

  STA(0, 0, 0); STA(0, 1, 0); STB(0, 0, 0); STB(0, 1, 0);
  STB(1, 0, 1);
  VMW(1);
  BAR();

  for (int it = 0; it < NITER; ++it) {
    const int t1 = 2 * it + 1;
    const int tn0 = (2 * it + 2 > NTm1) ? NTm1 : 2 * it + 2;
    const int tn1 = (2 * it + 3 > NTm1) ? NTm1 : 2 * it + 3;
    DSA(0, 0, 0); DSB(0, 0); STB(1, 1, t1); BAR(); MF(0); BAR();
    DSA(0, 1, 0);            STA(1, 0, t1); BAR(); MF(1); BAR();
    DSA(0, 0, 1); DSB(0, 1); STA(1, 1, t1); BAR(); MF(0); BAR();
    DSA(0, 1, 1);            STB(0, 0, tn0); VMW(1); BAR(); MF(1); BAR();
    DSA(1, 0, 0); DSB(1, 0); STB(0, 1, tn0); BAR(); MF(0); BAR();
    DSA(1, 1, 0);            STA(0, 0, tn0); BAR(); MF(1); BAR();
    DSA(1, 0, 1); DSB(1, 1); STA(0, 1, tn0); BAR(); MF(0); BAR();
    DSA(1, 1, 1);            STB(1, 0, tn1); VMW(1); BAR(); MF(1); BAR();
  }
  asm volatile("s_waitcnt vmcnt(0)" ::: "memory");
#undef STA
#undef STB
#undef DSA
#undef DSB
#undef MF

  const int rowbase = m0 + wm * 128;
  const int colbase = n0 + wn * 32;
  const float* rs = rowsum + z * 2048 + rowbase;
  float invv[8][4];
#pragma unroll
  for (int mi = 0; mi < 8; ++mi)
#pragma unroll
    for (int r = 0; r < 4; ++r) invv[mi][r] = 1.0f / rs[mi * 16 + quad * 4 + r];

  float* C = out + (int64_t)z * 2048 * 1024;
#pragma unroll
  for (int ni = 0; ni < 2; ++ni) {
    int col = colbase + ni * 16 + tr;
#pragma unroll
    for (int mi = 0; mi < 8; ++mi) {
      int row = rowbase + mi * 16 + quad * 4;
#pragma unroll
      for (int r = 0; r < 4; ++r)
        C[(int64_t)(row + r) * 1024 + col] = acc[mi][ni][r] * invv[mi][r];
    }
  }
}

// ------------------------------- launcher ----------------------------------
extern "C" void kernel_launch(void* const* d_in, const int* in_sizes, int n_in,
                              void* d_out, int out_size, void* d_ws,
                              size_t ws_size, hipStream_t stream) {
  const float* X = (const float*)d_in[0];        // (4,2048,1024) fp32
  const int* mask = (const int*)d_in[1];         // (4,2048) bool->int32
  const float* W = (const float*)d_in[2];        // (1024,3072) fp32
  const float* bias = (const float*)d_in[3];     // (3072,) fp32
  float* out = (float*)d_out;                    // (4,2048,1024) fp32

  char* ws = (char*)d_ws;
  auto alloc = [&](size_t bytes) {
    char* p = ws;
    ws += (bytes + 255) & ~(size_t)255;
    return p;
  };
  __hip_bfloat16* Xb = (__hip_bfloat16*)alloc(8192ULL * 1024 * 2);      // 16.8 MB
  __hip_bfloat16* Wt = (__hip_bfloat16*)alloc(3072ULL * 1024 * 2);      //  6.3 MB
  __hip_bfloat16* Q = (__hip_bfloat16*)alloc(8192ULL * 1024 * 2);       // 16.8 MB
  __hip_bfloat16* Kc = (__hip_bfloat16*)alloc(4ULL * 2048 * 1024 * 2);  // 16.8 MB
  __hip_bfloat16* Vt = (__hip_bfloat16*)alloc(4ULL * 1024 * 2048 * 2);  // 16.8 MB
  __hip_bfloat16* Sc = (__hip_bfloat16*)alloc(4ULL * 2048 * 2048 * 2);  // 33.6 MB
  float* rowsum = (float*)alloc(8192ULL * 4);                           // 32 KB
  int* idx = (int*)alloc(4ULL * 2048 * 4);
  int* cnt = (int*)alloc(64);
  int* cnt_pad = (int*)alloc(64);

  // 0) rowsum = 0 (ws is poisoned 0xAA before every launch)
  hipMemsetAsync(rowsum, 0, 8192ULL * 4, stream);
  // 1) X -> bf16
  cvt_f32_bf16<<<8192, 256, 0, stream>>>(X, Xb, 8192 * 1024);
  // 2) W -> W^T bf16  (Bt layout [N][K])
  transpose_cvt_f32<<<dim3(96, 32, 1), dim3(32, 8), 0, stream>>>(W, 3072, Wt,
                                                                 1024);
  // 3) mask -> compacted index list (cnt_pad now 256-aligned)
  mask_scan<<<4, 256, 0, stream>>>(mask, idx, cnt, cnt_pad);
  // 4) merged Q + K + V^T, 256x256 8-phase
  gemm_qkv<<<dim3(96, 1, 4), 512, 0, stream>>>(Xb, Wt, bias, idx, cnt,
                                               cnt_pad, Q, Kc, Vt);
  // 5) E = exp2(log2e/32 * Q@Kc^T) -> bf16, rowsum += per-row sums
  gemm_scores<<<dim3(128, 1, 4), 512, 0, stream>>>(
      Q, Kc, Sc, rowsum, cnt, cnt_pad, 0.03125f * 1.4426950408889634f);
  // 6) out = (E @ Vt^T) / rowsum  (fp32, K = cnt_pad)
  gemm_pv<<<dim3(64, 1, 4), 512, 0, stream>>>(Sc, Vt, out, rowsum, cnt_pad);
}